// Round 8
// baseline (224.013 us; speedup 1.0000x reference)
//
#include <hip/hip_runtime.h>
#include <hip/hip_bf16.h>
#include <math.h>

#define B_ 2
#define T_ 2048
#define D_ 1024
#define H_ 16
#define QSCALE (0.03125f * 1.44269504088896f)  // 1/sqrt(1024) * log2(e)

typedef _Float16 f16;
using f16x4 = __attribute__((ext_vector_type(4))) _Float16;
using f16x8 = __attribute__((ext_vector_type(8))) _Float16;
using f32x4 = __attribute__((ext_vector_type(4))) float;

__device__ __forceinline__ void gl16(const void* g, void* l) {
  __builtin_amdgcn_global_load_lds(
      (__attribute__((address_space(1))) void*)g,
      (__attribute__((address_space(3))) void*)l, 16, 0, 0);
}

__device__ __forceinline__ unsigned lds_a32(const void* p) {
  return (unsigned)(size_t)(__attribute__((address_space(3))) const char*)p;
}

// ---------------------------------------------------------------------------
// prep0: mask scan -> inv (compacted position per masked row, -1 if dropped)
// + nk (count per batch). One block per batch. Must run before prep1.
// ---------------------------------------------------------------------------
__global__ __launch_bounds__(256) void prep0(
    const int* __restrict__ mask, int* __restrict__ inv, int* __restrict__ nk) {
  __shared__ int cnt[256];
  const int b = blockIdx.x;
  const int tid = threadIdx.x;
  int loc[8];
  int c = 0;
#pragma unroll
  for (int i = 0; i < 8; ++i) {
    loc[i] = mask[b * T_ + tid * 8 + i];
    c += loc[i];
  }
  cnt[tid] = c;
  __syncthreads();
  for (int off = 1; off < 256; off <<= 1) {
    int vsh = (tid >= off) ? cnt[tid - off] : 0;
    __syncthreads();
    cnt[tid] += vsh;
    __syncthreads();
  }
  int pos = cnt[tid] - c;  // exclusive prefix
#pragma unroll
  for (int i = 0; i < 8; ++i) {
    const int t = tid * 8 + i;
    inv[b * T_ + t] = loc[i] ? pos : -1;
    pos += loc[i];
  }
  if (tid == 255) nk[b] = cnt[255];
}

// ---------------------------------------------------------------------------
// prep1: cvt_x (0..6143) + cvt_w transpose (6144..7167) + pack_bias
// (7168..7183). ROUND 8: k/v conversion COMPACTS rows through inv -- masked
// rows land at their compacted position, dropped rows are skipped. The K/V
// GEMMs then run on ~n rows instead of T (blocks beyond nkt*64 early-exit),
// cutting ~1/3 of total QKV GEMM work. Rows [n, nkt*64) of xkc/xvc stay
// garbage; the GEMM epilogue masks them to 0 (MFMA is row-contained, so
// garbage A rows only affect their own masked-out C rows).
// ---------------------------------------------------------------------------
__global__ __launch_bounds__(256) void prep1(
    const float* __restrict__ q, const float* __restrict__ k,
    const float* __restrict__ v, const int* __restrict__ inv,
    const float* __restrict__ Wq, const float* __restrict__ Wk,
    const float* __restrict__ Wv, const float* __restrict__ Wo,
    const float* __restrict__ bq, const float* __restrict__ bk,
    const float* __restrict__ bv, const float* __restrict__ bo,
    f16* __restrict__ xqkv, f16* __restrict__ Wt, float* __restrict__ bias) {
  __shared__ float sh[64][65];
  const int bid = blockIdx.x;
  const int tid = threadIdx.x;

  if (bid < 6144) {  // ---- cvt_x: fp32 -> f16 (k/v: compacted scatter) ----
    const int z = bid / 2048;
    const float* src = (z == 0) ? q : (z == 1) ? k : v;
    const size_t i = ((size_t)(bid % 2048) * 256 + tid) * 8;
    float4 a = *(const float4*)(src + i);
    float4 b4 = *(const float4*)(src + i + 4);
    f16x8 o;
    o[0] = (f16)a.x;  o[1] = (f16)a.y;  o[2] = (f16)a.z;  o[3] = (f16)a.w;
    o[4] = (f16)b4.x; o[5] = (f16)b4.y; o[6] = (f16)b4.z; o[7] = (f16)b4.w;
    if (z == 0) {
      *(f16x8*)(xqkv + i) = o;
    } else {
      const int tl = (int)(i >> 10);          // global row 0..4095
      const int bb = tl >> 11, t = tl & 2047;
      const int j = inv[bb * T_ + t];
      if (j >= 0)
        *(f16x8*)(xqkv + (size_t)z * 4194304 +
                  (((size_t)(bb * T_ + j)) << 10) + (i & 1023)) = o;
    }
  } else if (bid < 7168) {  // ---- cvt_w: W[K][N] fp32 -> Wt[N][K] f16 ----
    const int id = bid - 6144;
    const int z = id >> 8;
    const int k0 = ((id >> 4) & 15) * 64, n0 = (id & 15) * 64;
    const float* W = (z == 0) ? Wq : (z == 1) ? Wk : (z == 2) ? Wv : Wo;
    const int r = tid >> 2, c0 = (tid & 3) * 16;
#pragma unroll
    for (int i = 0; i < 4; ++i)
      *(float4*)&sh[r][c0 + 4 * i] =
          *(const float4*)&W[(size_t)(k0 + r) * 1024 + n0 + c0 + 4 * i];
    __syncthreads();
    f16 tmp[16];
#pragma unroll
    for (int i = 0; i < 16; ++i) tmp[i] = (f16)sh[c0 + i][r];
    f16* dst = Wt + (size_t)z * 1048576 + (size_t)(n0 + r) * 1024 + k0 + c0;
    *(f16x8*)dst = *(f16x8*)&tmp[0];
    *(f16x8*)(dst + 8) = *(f16x8*)&tmp[8];
  } else {  // ---- pack_bias ----
    const int i = (bid - 7168) * 256 + tid;
    const int z = i >> 10;
    const float* s = (z == 0) ? bq : (z == 1) ? bk : (z == 2) ? bv : bo;
    bias[i] = s[i & 1023];
  }
}

// ---------------------------------------------------------------------------
// gemm_r2: QKV projection GEMM, 128x128 tile, BK=32, 256 thr / 4 waves,
// ring-2 LDS (32KB -> 3+ blocks/CU, 12 waves/CU), counted vmcnt, asm
// ds_read_b128 + bare waits + asm barriers, XOR swizzle (0 conflicts).
// ROUND 8: z>=1 operates on COMPACTED inputs (xkc/xvc): blocks whose row
// range lies beyond nkt*64 early-exit (saves ~1/3 of total work at ~50%
// mask density); epilogue masks rows j>=n to 0 (khc pad-key semantics:
// zero rows -> S=0 -> p=1 -> corrected via lsum-=npad in attn).
// Ring-2 safety: tile t+2 reuses slot t&1 only after COMPUTE(t)'s
// lgkmcnt(0)+barrier retired all reads. vmcnt(4) at compute of tile t.
// ---------------------------------------------------------------------------
__global__ __launch_bounds__(256, 4) void gemm_r2(
    const f16* __restrict__ Xb, const f16* __restrict__ Wtb,
    const float* __restrict__ biasb, void* __restrict__ C0,
    void* __restrict__ C1, void* __restrict__ C2,
    const int* __restrict__ nkd, float qscale) {
  __shared__ __align__(16) char lds[32768];  // [A0 8K][B0 8K][A1 8K][B1 8K]
  const int z = blockIdx.z;
  const int m0 = blockIdx.y * 128, n0 = blockIdx.x * 128;

  if (z) {  // compacted K/V: skip blocks fully beyond this batch's live rows
    const int nb = nkd[m0 >> 11];
    const int lim = ((nb + 63) >> 6) << 6;  // nkt*64
    if ((m0 & 2047) >= lim) return;
  }

  const f16* X  = Xb  + (size_t)z * (4096 * 1024);
  const f16* Wt = Wtb + (size_t)z * (1024 * 1024);
  const float* bias = biasb + (size_t)z * 1024;
  f16* C = (f16*)((z == 0) ? C0 : (z == 1) ? C1 : C2);
  const float scl = (z == 0) ? qscale : 1.f;

  const int tid = threadIdx.x;
  const int wave = tid >> 6, lane = tid & 63;
  const int quad = lane >> 4, l16 = lane & 15;
  const int wm = wave & 1, wn = wave >> 1;  // 2 x 2 wave grid

  // staging: 256 threads x 16B = rows 0..63 of a panel; second gl16 at
  // +4096 covers rows 64..127. src chunk = (tid&3) ^ ((row>>1)&3)
  const int r0 = tid >> 2;
  const int ssw = (tid & 3) ^ ((r0 >> 1) & 3);
  const f16* ap0 = X  + (size_t)(m0 + r0) * 1024 + ssw * 8;
  const f16* ap1 = ap0 + (size_t)64 * 1024;
  const f16* bp0 = Wt + (size_t)(n0 + r0) * 1024 + ssw * 8;
  const f16* bp1 = bp0 + (size_t)64 * 1024;
  char* al = lds + tid * 16;
  char* bl = lds + 8192 + tid * 16;

  // read-side swizzle: frag at (row, quad) reads chunk quad ^ ((l16>>1)&3)
  const int sw16 = 16 * (quad ^ ((l16 >> 1) & 3));
  const unsigned a32 = lds_a32(lds + (64 * wm + l16) * 64 + sw16);
  const unsigned b32 = lds_a32(lds + 8192 + (64 * wn + l16) * 64 + sw16);

  f32x4 acc[4][4] = {};

#define R2_ISSUE(tt, sl) do {                                               \
    gl16(ap0 + (tt) * 32, al + (sl) * 16384);                               \
    gl16(ap1 + (tt) * 32, al + (sl) * 16384 + 4096);                        \
    gl16(bp0 + (tt) * 32, bl + (sl) * 16384);                               \
    gl16(bp1 + (tt) * 32, bl + (sl) * 16384 + 4096);                        \
    __builtin_amdgcn_sched_barrier(0);                                      \
  } while (0)

#define R2_WAIT(n) do {                                                     \
    asm volatile("s_waitcnt vmcnt(" #n ")");                                \
    __builtin_amdgcn_sched_barrier(0);                                      \
  } while (0)

#define R2_BAR() do {                                                       \
    __builtin_amdgcn_sched_barrier(0);                                      \
    asm volatile("s_barrier");                                              \
    __builtin_amdgcn_sched_barrier(0);                                      \
  } while (0)

#define R2_STR_(x) #x
#define R2_STR(x) R2_STR_(x)
#define DSR(dst, base, OFF)                                                 \
  asm volatile("ds_read_b128 %0, %1 offset:" R2_STR(OFF)                    \
               : "=v"(dst) : "v"(base))

#define R2_COMPUTE(sl) do {                                                 \
    R2_BAR();                                                               \
    const unsigned aa = a32 + (sl) * 16384;                                 \
    const unsigned bb = b32 + (sl) * 16384;                                 \
    f16x8 af[4], bf[4];                                                     \
    DSR(af[0], aa, 0);    DSR(af[1], aa, 1024);                             \
    DSR(bf[0], bb, 0);    DSR(bf[1], bb, 1024);                             \
    DSR(bf[2], bb, 2048); DSR(bf[3], bb, 3072);                             \
    DSR(af[2], aa, 2048); DSR(af[3], aa, 3072);                             \
    asm volatile("s_waitcnt lgkmcnt(2)");                                   \
    __builtin_amdgcn_sched_barrier(0);                                      \
    __builtin_amdgcn_s_setprio(1);                                          \
    _Pragma("unroll")                                                       \
    for (int mi = 0; mi < 2; ++mi)                                          \
      _Pragma("unroll")                                                     \
      for (int ni = 0; ni < 4; ++ni)                                        \
        acc[mi][ni] = __builtin_amdgcn_mfma_f32_16x16x32_f16(               \
            af[mi], bf[ni], acc[mi][ni], 0, 0, 0);                          \
    asm volatile("s_waitcnt lgkmcnt(0)");                                   \
    __builtin_amdgcn_sched_barrier(0);                                      \
    _Pragma("unroll")                                                       \
    for (int mi = 2; mi < 4; ++mi)                                          \
      _Pragma("unroll")                                                     \
      for (int ni = 0; ni < 4; ++ni)                                        \
        acc[mi][ni] = __builtin_amdgcn_mfma_f32_16x16x32_f16(               \
            af[mi], bf[ni], acc[mi][ni], 0, 0, 0);                          \
    __builtin_amdgcn_s_setprio(0);                                          \
    R2_BAR();                                                               \
  } while (0)

  // K = 1024 -> 32 K-tiles of 32. Ring-2: slot = tile & 1.
  R2_ISSUE(0, 0);
  for (int j = 0; j < 15; ++j) {  // tiles 2j, 2j+1 (0..29)
    R2_ISSUE(2 * j + 1, 1); R2_WAIT(4); R2_COMPUTE(0);
    R2_ISSUE(2 * j + 2, 0); R2_WAIT(4); R2_COMPUTE(1);
  }
  R2_ISSUE(31, 1); R2_WAIT(4); R2_COMPUTE(0);  // tile 30
  R2_WAIT(0); R2_COMPUTE(1);                   // tile 31

#undef R2_ISSUE
#undef R2_WAIT
#undef R2_BAR
#undef DSR
#undef R2_STR
#undef R2_STR_
#undef R2_COMPUTE

  const int cm = m0 + 64 * wm + 4 * quad;
  const int cn = n0 + 64 * wn + l16;
  float bv[4];
#pragma unroll
  for (int ni = 0; ni < 4; ++ni) bv[ni] = bias[cn + 16 * ni];

  if (z == 0) {
#pragma unroll
    for (int mi = 0; mi < 4; ++mi)
#pragma unroll
      for (int r = 0; r < 4; ++r) {
        f16* row = C + (size_t)(cm + 16 * mi + r) * 1024;
#pragma unroll
        for (int ni = 0; ni < 4; ++ni)
          row[cn + 16 * ni] = (f16)((acc[mi][ni][r] + bv[ni]) * scl);
      }
  } else {  // compacted: rows j >= n masked to 0 (pad-key zero semantics)
    const int nb = nkd[m0 >> 11];
#pragma unroll
    for (int mi = 0; mi < 4; ++mi)
#pragma unroll
      for (int r = 0; r < 4; ++r) {
        const int m = cm + 16 * mi + r;
        const bool ok = (m & 2047) < nb;
        f16* row = C + (size_t)m * 1024;
#pragma unroll
        for (int ni = 0; ni < 4; ++ni)
          row[cn + 16 * ni] = ok ? (f16)(acc[mi][ni][r] + bv[ni]) : (f16)0.f;
      }
  }
}

// ---------------------------------------------------------------------------
// m97-style GEMM (kept for the output projection): C[M,N] = X @ Wt^T + bias.
// ---------------------------------------------------------------------------
template <int TM, typename OT>
__global__ __launch_bounds__(256) void gemm_bt(
    const f16* __restrict__ Xb, const f16* __restrict__ Wtb,
    const float* __restrict__ biasb, void* __restrict__ C0,
    const int* __restrict__ unused, int M, int N, int K, float qscale) {
  constexpr int FM = TM / 32;
  __shared__ __align__(16) f16 As[TM * 32];
  __shared__ __align__(16) f16 Bs[128 * 32];
  const f16* X  = Xb;
  const f16* Wt = Wtb;
  const float* bias = biasb;
  OT* C = (OT*)C0;
  const float scl = qscale;

  const int tid = threadIdx.x;
  const int wave = tid >> 6, lane = tid & 63;
  const int quad = lane >> 4, l16 = lane & 15;
  const int wm = wave & 1, wn = wave >> 1;
  const int m0 = blockIdx.y * TM, n0 = blockIdx.x * 128;

  f32x4 acc[FM][4] = {};

  const f16* asrc = X  + (size_t)(m0 + (tid >> 2)) * K + (tid & 3) * 8;
  const f16* bsrc = Wt + (size_t)(n0 + (tid >> 2)) * K + (tid & 3) * 8;
  char* aldst = (char*)As + tid * 16;
  char* bldst = (char*)Bs + tid * 16;
  const size_t rstep = (size_t)64 * K;

  const int NK = K >> 5;
  for (int kt = 0; kt < NK; ++kt) {
    if (kt) __syncthreads();
    gl16(asrc, aldst);
    if constexpr (TM == 128) gl16(asrc + rstep, aldst + 4096);
    gl16(bsrc, bldst);
    gl16(bsrc + rstep, bldst + 4096);
    asrc += 32; bsrc += 32;
    __syncthreads();

    f16x8 af[FM], bf[4];
#pragma unroll
    for (int t = 0; t < FM; ++t)
      af[t] = *(const f16x8*)&As[((TM / 2) * wm + 16 * t + l16) * 32 + quad * 8];
#pragma unroll
    for (int t = 0; t < 4; ++t)
      bf[t] = *(const f16x8*)&Bs[(64 * wn + 16 * t + l16) * 32 + quad * 8];
#pragma unroll
    for (int i = 0; i < FM; ++i)
#pragma unroll
      for (int j = 0; j < 4; ++j)
        acc[i][j] = __builtin_amdgcn_mfma_f32_16x16x32_f16(af[i], bf[j], acc[i][j], 0, 0, 0);
  }

  const int cm = m0 + (TM / 2) * wm + 4 * quad;
  const int cn = n0 + 64 * wn + l16;
  float bv[4];
#pragma unroll
  for (int tn = 0; tn < 4; ++tn) bv[tn] = bias[cn + 16 * tn];

#pragma unroll
  for (int tm = 0; tm < FM; ++tm)
#pragma unroll
    for (int r = 0; r < 4; ++r) {
      OT* row = C + (size_t)(cm + 16 * tm + r) * N;
#pragma unroll
      for (int tn = 0; tn < 4; ++tn)
        row[cn + 16 * tn] = (OT)((acc[tm][tn][r] + bv[tn]) * scl);
    }
}

// ---------------------------------------------------------------------------
// vtrans: transpose compacted V. vhT[bh][dh][j] = vhc[b*T+j][h*64+dh],
// zeros for pad j; tiles >= nkt untouched (attn never reads them).
// (Gather removed: vhc rows are already compacted by the z=2 GEMM.)
// ---------------------------------------------------------------------------
__global__ __launch_bounds__(256) void vtrans(
    const f16* __restrict__ vhc, const int* __restrict__ nk,
    f16* __restrict__ vhT) {
  const int tt = blockIdx.x, bh = blockIdx.y;
  const int b = bh >> 4, h = bh & 15;
  const int n = nk[b];
  const int nkt = (n + 63) >> 6;
  if (tt >= nkt) return;
  __shared__ f16 t[64][72];
  const int tid = threadIdx.x;
  const int r = tid >> 2, cq = 16 * (tid & 3);

  const int j = tt * 64 + r;
  uint4 v0 = {0u, 0u, 0u, 0u}, v1 = {0u, 0u, 0u, 0u};
  if (j < n) {
    const uint4* src = (const uint4*)(vhc + ((size_t)b * T_ + j) * D_ + h * 64 + cq);
    v0 = src[0]; v1 = src[1];
  }
  *(uint4*)&t[r][cq]     = v0;
  *(uint4*)&t[r][cq + 8] = v1;
  __syncthreads();

  f16 tmp[16];
#pragma unroll
  for (int xx = 0; xx < 16; ++xx) {
    int x = (xx + r) & 15;
    tmp[x] = t[cq + x][r];
  }
  f16* dst = vhT + ((size_t)bh * 64 + r) * T_ + tt * 64 + cq;
  *(uint4*)&dst[0] = *(uint4*)&tmp[0];
  *(uint4*)&dst[8] = *(uint4*)&tmp[8];
}

// ---------------------------------------------------------------------------
// Flash attention over compacted keys. Block = 128 q-rows (grid 16 x 32),
// 512 threads / 8 waves; each wave owns 16 q-rows. 16 waves/CU.
// Q frags direct from global, cached in regs. qh pre-scaled by SCALE*log2e
// -> P = exp2(S); pad keys contribute p=1, corrected via lsum -= npad.
// ---------------------------------------------------------------------------
__global__ __launch_bounds__(512) void attn_mfma(
    const f16* __restrict__ qh, const f16* __restrict__ khc,
    const f16* __restrict__ vhT, const int* __restrict__ nkd,
    f16* __restrict__ oat) {
  __shared__ f16 Ks[64][72];     // [key][dh]
  __shared__ f16 Vt[64][72];     // [dh][key]
  __shared__ f16 Ps[8][16][72];  // per-wave [qrow][key]

  const int qt = blockIdx.x, bh = blockIdx.y;
  const int b = bh >> 4, h = bh & 15;
  const int tid = threadIdx.x;
  const int wave = tid >> 6, lane = tid & 63;
  const int quad = lane >> 4, l16 = lane & 15;
  const int sr = tid >> 3, sq = 8 * (tid & 7);  // 512 thr: 1 uint4 each for K,V

  const int n = nkd[b];
  const int nkt = (n + 63) >> 6;
  const int npad = (nkt << 6) - n;

  // Q fragments direct from global: row qt*128 + wave*16 + l16
  f16x8 qf[2];
  {
    const f16* qp = qh + ((size_t)(b * T_ + qt * 128 + wave * 16 + l16)) * D_ + h * 64 + quad * 8;
    qf[0] = *(const f16x8*)qp;
    qf[1] = *(const f16x8*)(qp + 32);
  }

  float lsum = 0.f;
  f32x4 o[4] = {};

  const f16* kbase = khc + (size_t)b * T_ * D_ + h * 64;
  const f16* vbase = vhT + ((size_t)bh * 64 + sr) * T_;

  uint4 kr, vr;
  auto load_kv = [&](int kt) {
    kr = *(const uint4*)(kbase + (size_t)(kt * 64 + sr) * D_ + sq);
    vr = *(const uint4*)(vbase + kt * 64 + sq);
  };
  if (nkt > 0) load_kv(0);

  for (int kt = 0; kt < nkt; ++kt) {
    *(uint4*)&Ks[sr][sq] = kr;
    *(uint4*)&Vt[sr][sq] = vr;
    __syncthreads();
    if (kt + 1 < nkt) load_kv(kt + 1);  // prefetch next tile into regs

    // ---- S^T = K Q^T : D[m=key][n=qrow] ----
#pragma unroll
    for (int tn = 0; tn < 4; ++tn) {
      f16x8 kf0 = *(const f16x8*)&Ks[16 * tn + l16][quad * 8];
      f16x8 kf1 = *(const f16x8*)&Ks[16 * tn + l16][32 + quad * 8];
      f32x4 s = {0.f, 0.f, 0.f, 0.f};
      s = __builtin_amdgcn_mfma_f32_16x16x32_f16(kf0, qf[0], s, 0, 0, 0);
      s = __builtin_amdgcn_mfma_f32_16x16x32_f16(kf1, qf[1], s, 0, 0, 0);
      float p0 = exp2f(s[0]), p1 = exp2f(s[1]);
      float p2 = exp2f(s[2]), p3 = exp2f(s[3]);
      lsum += (p0 + p1) + (p2 + p3);
      f16x4 pk;
      pk[0] = (f16)p0; pk[1] = (f16)p1; pk[2] = (f16)p2; pk[3] = (f16)p3;
      *(f16x4*)&Ps[wave][l16][16 * tn + 4 * quad] = pk;
    }

    // ---- O += P V ----
    f16x8 pf0 = *(const f16x8*)&Ps[wave][l16][quad * 8];
    f16x8 pf1 = *(const f16x8*)&Ps[wave][l16][32 + quad * 8];
#pragma unroll
    for (int t = 0; t < 4; ++t) {
      f16x8 vf0 = *(const f16x8*)&Vt[16 * t + l16][quad * 8];
      f16x8 vf1 = *(const f16x8*)&Vt[16 * t + l16][32 + quad * 8];
      o[t] = __builtin_amdgcn_mfma_f32_16x16x32_f16(pf0, vf0, o[t], 0, 0, 0);
      o[t] = __builtin_amdgcn_mfma_f32_16x16x32_f16(pf1, vf1, o[t], 0, 0, 0);
    }
    __syncthreads();
  }

  {
    float ls = lsum;
    ls += __shfl_xor(ls, 16);   // quads hold disjoint key subsets
    ls += __shfl_xor(ls, 32);
    ls -= (float)npad;
    const size_t orow = (size_t)(b * T_ + qt * 128 + wave * 16 + 4 * quad);
#pragma unroll
    for (int r = 0; r < 4; ++r) {
      const float iv = 1.f / __shfl(ls, 4 * quad + r);
#pragma unroll
      for (int t = 0; t < 4; ++t)
        oat[(orow + r) * D_ + h * 64 + 16 * t + l16] = (f16)(o[t][r] * iv);
    }
  }
}

// ---------------------------------------------------------------------------
extern "C" void kernel_launch(void* const* d_in, const int* in_sizes, int n_in,
                              void* d_out, int out_size, void* d_ws, size_t ws_size,
                              hipStream_t stream) {
  const float* q  = (const float*)d_in[0];
  const float* k  = (const float*)d_in[1];
  const float* v  = (const float*)d_in[2];
  const int* mask = (const int*)d_in[3];
  const float* Wq = (const float*)d_in[4];
  const float* bq = (const float*)d_in[5];
  const float* Wk = (const float*)d_in[6];
  const float* bk = (const float*)d_in[7];
  const float* Wv = (const float*)d_in[8];
  const float* bv = (const float*)d_in[9];
  const float* Wo = (const float*)d_in[10];
  const float* bo = (const float*)d_in[11];
  float* out = (float*)d_out;

  // ws layout (bytes):
  //  0        xq (8MB)  -> vhT after gemm
  //  8388608  xkc (8MB) -> oat after gemm
  //  16777216 xvc (8MB)
  //  25165824 Wt (8MB)
  //  33554432 qh (8MB)
  //  41943040 vhc (8MB)
  //  50331648 khc (8MB)
  //  58720256 bias(16KB) | inv(16KB) | nk(8B)
  char* ws = (char*)d_ws;
  f16* xqkv  = (f16*)(ws);
  f16* Wt    = (f16*)(ws + 25165824);
  f16* qh    = (f16*)(ws + 33554432);
  f16* vhc   = (f16*)(ws + 41943040);
  f16* khc   = (f16*)(ws + 50331648);
  float* bsw = (float*)(ws + 58720256);
  int* inv   = (int*)(ws + 58736640);
  int* nk    = (int*)(ws + 58753024);
  f16* vhT   = (f16*)(ws);             // aliases xq (dead after gemm)
  f16* oat   = (f16*)(ws + 8388608);   // aliases xkc (dead after gemm)

  const int M = B_ * T_;  // 4096
  dim3 blk(256);

  prep0<<<dim3(2), blk, 0, stream>>>(mask, inv, nk);

  prep1<<<dim3(7184), blk, 0, stream>>>(q, k, v, inv, Wq, Wk, Wv, Wo,
                                        bq, bk, bv, bo, xqkv, Wt, bsw);

  gemm_r2<<<dim3(8, 32, 3), blk, 0, stream>>>(
      xqkv, Wt, bsw, qh, khc, vhc, nk, QSCALE);

  vtrans<<<dim3(32, 32), blk, 0, stream>>>(vhc, nk, vhT);

  attn_mfma<<<dim3(16, 32), dim3(512), 0, stream>>>(qh, khc, vhT, nk, oat);

  gemm_bt<64, float><<<dim3(8, 64, 1), blk, 0, stream>>>(
      oat, Wt + 3145728, bsw + 3072, out, nullptr, M, D_, D_, 1.f);
}

// Round 9
// 216.981 us; speedup vs baseline: 1.0324x; 1.0324x over previous
//
#include <hip/hip_runtime.h>
#include <hip/hip_bf16.h>
#include <math.h>

#define B_ 2
#define T_ 2048
#define D_ 1024
#define H_ 16
#define QSCALE (0.03125f * 1.44269504088896f)  // 1/sqrt(1024) * log2(e)

typedef _Float16 f16;
using f16x4 = __attribute__((ext_vector_type(4))) _Float16;
using f16x8 = __attribute__((ext_vector_type(8))) _Float16;
using f32x4 = __attribute__((ext_vector_type(4))) float;

__device__ __forceinline__ void gl16(const void* g, void* l) {
  __builtin_amdgcn_global_load_lds(
      (__attribute__((address_space(1))) void*)g,
      (__attribute__((address_space(3))) void*)l, 16, 0, 0);
}

__device__ __forceinline__ unsigned lds_a32(const void* p) {
  return (unsigned)(size_t)(__attribute__((address_space(3))) const char*)p;
}

// ---------------------------------------------------------------------------
// prep0: mask scan -> inv (compacted position per masked row, -1 if dropped)
// + nk (count per batch). One block per batch. Must run before prep1.
// ---------------------------------------------------------------------------
__global__ __launch_bounds__(256) void prep0(
    const int* __restrict__ mask, int* __restrict__ inv, int* __restrict__ nk) {
  __shared__ int cnt[256];
  const int b = blockIdx.x;
  const int tid = threadIdx.x;
  int loc[8];
  int c = 0;
#pragma unroll
  for (int i = 0; i < 8; ++i) {
    loc[i] = mask[b * T_ + tid * 8 + i];
    c += loc[i];
  }
  cnt[tid] = c;
  __syncthreads();
  for (int off = 1; off < 256; off <<= 1) {
    int vsh = (tid >= off) ? cnt[tid - off] : 0;
    __syncthreads();
    cnt[tid] += vsh;
    __syncthreads();
  }
  int pos = cnt[tid] - c;  // exclusive prefix
#pragma unroll
  for (int i = 0; i < 8; ++i) {
    const int t = tid * 8 + i;
    inv[b * T_ + t] = loc[i] ? pos : -1;
    pos += loc[i];
  }
  if (tid == 255) nk[b] = cnt[255];
}

// ---------------------------------------------------------------------------
// prep1: cvt_x (0..6143) + cvt_w transpose (6144..7167) + pack_bias
// (7168..7183). k/v conversion COMPACTS rows through inv; dropped rows
// skipped. Rows [n, nkt*64) of xkc/xvc stay garbage; the GEMM epilogue
// masks them to 0.
// ---------------------------------------------------------------------------
__global__ __launch_bounds__(256) void prep1(
    const float* __restrict__ q, const float* __restrict__ k,
    const float* __restrict__ v, const int* __restrict__ inv,
    const float* __restrict__ Wq, const float* __restrict__ Wk,
    const float* __restrict__ Wv, const float* __restrict__ Wo,
    const float* __restrict__ bq, const float* __restrict__ bk,
    const float* __restrict__ bv, const float* __restrict__ bo,
    f16* __restrict__ xqkv, f16* __restrict__ Wt, float* __restrict__ bias) {
  __shared__ float sh[64][65];
  const int bid = blockIdx.x;
  const int tid = threadIdx.x;

  if (bid < 6144) {  // ---- cvt_x: fp32 -> f16 (k/v: compacted scatter) ----
    const int z = bid / 2048;
    const float* src = (z == 0) ? q : (z == 1) ? k : v;
    const size_t i = ((size_t)(bid % 2048) * 256 + tid) * 8;
    float4 a = *(const float4*)(src + i);
    float4 b4 = *(const float4*)(src + i + 4);
    f16x8 o;
    o[0] = (f16)a.x;  o[1] = (f16)a.y;  o[2] = (f16)a.z;  o[3] = (f16)a.w;
    o[4] = (f16)b4.x; o[5] = (f16)b4.y; o[6] = (f16)b4.z; o[7] = (f16)b4.w;
    if (z == 0) {
      *(f16x8*)(xqkv + i) = o;
    } else {
      const int tl = (int)(i >> 10);          // global row 0..4095
      const int bb = tl >> 11, t = tl & 2047;
      const int j = inv[bb * T_ + t];
      if (j >= 0)
        *(f16x8*)(xqkv + (size_t)z * 4194304 +
                  (((size_t)(bb * T_ + j)) << 10) + (i & 1023)) = o;
    }
  } else if (bid < 7168) {  // ---- cvt_w: W[K][N] fp32 -> Wt[N][K] f16 ----
    const int id = bid - 6144;
    const int z = id >> 8;
    const int k0 = ((id >> 4) & 15) * 64, n0 = (id & 15) * 64;
    const float* W = (z == 0) ? Wq : (z == 1) ? Wk : (z == 2) ? Wv : Wo;
    const int r = tid >> 2, c0 = (tid & 3) * 16;
#pragma unroll
    for (int i = 0; i < 4; ++i)
      *(float4*)&sh[r][c0 + 4 * i] =
          *(const float4*)&W[(size_t)(k0 + r) * 1024 + n0 + c0 + 4 * i];
    __syncthreads();
    f16 tmp[16];
#pragma unroll
    for (int i = 0; i < 16; ++i) tmp[i] = (f16)sh[c0 + i][r];
    f16* dst = Wt + (size_t)z * 1048576 + (size_t)(n0 + r) * 1024 + k0 + c0;
    *(f16x8*)dst = *(f16x8*)&tmp[0];
    *(f16x8*)(dst + 8) = *(f16x8*)&tmp[8];
  } else {  // ---- pack_bias ----
    const int i = (bid - 7168) * 256 + tid;
    const int z = i >> 10;
    const float* s = (z == 0) ? bq : (z == 1) ? bk : (z == 2) ? bv : bo;
    bias[i] = s[i & 1023];
  }
}

// ---------------------------------------------------------------------------
// gemm_r4: 128x128 tile, BK=32, 256 thr / 4 waves, RING-4 LDS (64KB).
// ROUND 9: 64KB LDS caps residency at 2 blocks/CU -> the 768-block QKV grid
// has 256 blocks QUEUED -> hardware backfill redistributes live work as
// dead (compaction-skipped) blocks retire. Round 8's flat result was a
// makespan artifact: at 3 blocks/CU everything was resident at once and the
// 144 CUs holding 3 live blocks set the wall; queueing fixes the balance.
// Ring-4 also deepens the prefetch pipeline (vmcnt(12): 3 tiles in flight).
// Same asm machinery as verified rounds 4-8: asm ds_read_b128, bare
// waitcnts, asm s_barrier, XOR swizzle both-sides (0 conflicts).
// Template: OT=output type; CMP=K/V compaction mode (z>=1 early-exit +
// masked epilogue). Out-proj reuses this kernel with OT=float, CMP=false.
// Ring-4 safety: tile t+4 reuses slot t&3 only after COMPUTE(t)'s
// lgkmcnt(0)+barrier retired all reads of that slot in every wave.
// ---------------------------------------------------------------------------
template <typename OT, bool CMP>
__global__ __launch_bounds__(256, 4) void gemm_r4(
    const f16* __restrict__ Xb, const f16* __restrict__ Wtb,
    const float* __restrict__ biasb, void* __restrict__ C0,
    void* __restrict__ C1, void* __restrict__ C2,
    const int* __restrict__ nkd, float qscale) {
  __shared__ __align__(16) char lds[65536];  // 4 x [A 8K | B 8K]
  const int z = blockIdx.z;
  const int m0 = blockIdx.y * 128, n0 = blockIdx.x * 128;

  if (CMP && z) {  // compacted K/V: skip blocks beyond this batch's live rows
    const int nb = nkd[m0 >> 11];
    const int lim = ((nb + 63) >> 6) << 6;  // nkt*64
    if ((m0 & 2047) >= lim) return;
  }

  const f16* X  = Xb  + (size_t)z * (4096 * 1024);
  const f16* Wt = Wtb + (size_t)z * (1024 * 1024);
  const float* bias = biasb + (size_t)z * 1024;
  OT* C = (OT*)((z == 0) ? C0 : (z == 1) ? C1 : C2);
  const float scl = (z == 0) ? qscale : 1.f;

  const int tid = threadIdx.x;
  const int wave = tid >> 6, lane = tid & 63;
  const int quad = lane >> 4, l16 = lane & 15;
  const int wm = wave & 1, wn = wave >> 1;  // 2 x 2 wave grid

  // staging: 256 threads x 16B = rows 0..63 of a panel; second gl16 at
  // +4096 covers rows 64..127. src chunk = (tid&3) ^ ((row>>1)&3)
  const int r0 = tid >> 2;
  const int ssw = (tid & 3) ^ ((r0 >> 1) & 3);
  const f16* ap0 = X  + (size_t)(m0 + r0) * 1024 + ssw * 8;
  const f16* ap1 = ap0 + (size_t)64 * 1024;
  const f16* bp0 = Wt + (size_t)(n0 + r0) * 1024 + ssw * 8;
  const f16* bp1 = bp0 + (size_t)64 * 1024;
  char* al = lds + tid * 16;
  char* bl = lds + 8192 + tid * 16;

  // read-side swizzle: frag at (row, quad) reads chunk quad ^ ((l16>>1)&3)
  const int sw16 = 16 * (quad ^ ((l16 >> 1) & 3));
  const unsigned a32 = lds_a32(lds + (64 * wm + l16) * 64 + sw16);
  const unsigned b32 = lds_a32(lds + 8192 + (64 * wn + l16) * 64 + sw16);

  f32x4 acc[4][4] = {};

#define R4_ISSUE(tt, sl) do {                                               \
    gl16(ap0 + (tt) * 32, al + (sl) * 16384);                               \
    gl16(ap1 + (tt) * 32, al + (sl) * 16384 + 4096);                        \
    gl16(bp0 + (tt) * 32, bl + (sl) * 16384);                               \
    gl16(bp1 + (tt) * 32, bl + (sl) * 16384 + 4096);                        \
    __builtin_amdgcn_sched_barrier(0);                                      \
  } while (0)

#define R4_WAIT(n) do {                                                     \
    asm volatile("s_waitcnt vmcnt(" #n ")");                                \
    __builtin_amdgcn_sched_barrier(0);                                      \
  } while (0)

#define R4_BAR() do {                                                       \
    __builtin_amdgcn_sched_barrier(0);                                      \
    asm volatile("s_barrier");                                              \
    __builtin_amdgcn_sched_barrier(0);                                      \
  } while (0)

#define R4_STR_(x) #x
#define R4_STR(x) R4_STR_(x)
#define DSR(dst, base, OFF)                                                 \
  asm volatile("ds_read_b128 %0, %1 offset:" R4_STR(OFF)                    \
               : "=v"(dst) : "v"(base))

#define R4_COMPUTE(sl) do {                                                 \
    R4_BAR();                                                               \
    const unsigned aa = a32 + (sl) * 16384;                                 \
    const unsigned bb = b32 + (sl) * 16384;                                 \
    f16x8 af[4], bf[4];                                                     \
    DSR(af[0], aa, 0);    DSR(af[1], aa, 1024);                             \
    DSR(bf[0], bb, 0);    DSR(bf[1], bb, 1024);                             \
    DSR(bf[2], bb, 2048); DSR(bf[3], bb, 3072);                             \
    DSR(af[2], aa, 2048); DSR(af[3], aa, 3072);                             \
    asm volatile("s_waitcnt lgkmcnt(2)");                                   \
    __builtin_amdgcn_sched_barrier(0);                                      \
    __builtin_amdgcn_s_setprio(1);                                          \
    _Pragma("unroll")                                                       \
    for (int mi = 0; mi < 2; ++mi)                                          \
      _Pragma("unroll")                                                     \
      for (int ni = 0; ni < 4; ++ni)                                        \
        acc[mi][ni] = __builtin_amdgcn_mfma_f32_16x16x32_f16(               \
            af[mi], bf[ni], acc[mi][ni], 0, 0, 0);                          \
    asm volatile("s_waitcnt lgkmcnt(0)");                                   \
    __builtin_amdgcn_sched_barrier(0);                                      \
    _Pragma("unroll")                                                       \
    for (int mi = 2; mi < 4; ++mi)                                          \
      _Pragma("unroll")                                                     \
      for (int ni = 0; ni < 4; ++ni)                                        \
        acc[mi][ni] = __builtin_amdgcn_mfma_f32_16x16x32_f16(               \
            af[mi], bf[ni], acc[mi][ni], 0, 0, 0);                          \
    __builtin_amdgcn_s_setprio(0);                                          \
    R4_BAR();                                                               \
  } while (0)

  // K = 1024 -> 32 K-tiles of 32. Ring-4: slot = tile & 3; 3 tiles ahead.
  R4_ISSUE(0, 0); R4_ISSUE(1, 1); R4_ISSUE(2, 2);

  for (int j = 0; j < 7; ++j) {  // tiles 4j .. 4j+3 (0..27)
    const int t4 = j * 4;
    R4_ISSUE(t4 + 3, 3); R4_WAIT(12); R4_COMPUTE(0);
    R4_ISSUE(t4 + 4, 0); R4_WAIT(12); R4_COMPUTE(1);
    R4_ISSUE(t4 + 5, 1); R4_WAIT(12); R4_COMPUTE(2);
    R4_ISSUE(t4 + 6, 2); R4_WAIT(12); R4_COMPUTE(3);
  }
  R4_ISSUE(31, 3); R4_WAIT(12); R4_COMPUTE(0);  // tile 28
  R4_WAIT(8);  R4_COMPUTE(1);                   // tile 29
  R4_WAIT(4);  R4_COMPUTE(2);                   // tile 30
  R4_WAIT(0);  R4_COMPUTE(3);                   // tile 31

#undef R4_ISSUE
#undef R4_WAIT
#undef R4_BAR
#undef DSR
#undef R4_STR
#undef R4_STR_
#undef R4_COMPUTE

  const int cm = m0 + 64 * wm + 4 * quad;
  const int cn = n0 + 64 * wn + l16;
  float bv[4];
#pragma unroll
  for (int ni = 0; ni < 4; ++ni) bv[ni] = bias[cn + 16 * ni];

  if (!CMP || z == 0) {
#pragma unroll
    for (int mi = 0; mi < 4; ++mi)
#pragma unroll
      for (int r = 0; r < 4; ++r) {
        OT* row = C + (size_t)(cm + 16 * mi + r) * 1024;
#pragma unroll
        for (int ni = 0; ni < 4; ++ni)
          row[cn + 16 * ni] = (OT)((acc[mi][ni][r] + bv[ni]) * scl);
      }
  } else {  // compacted: rows j >= n masked to 0 (pad-key zero semantics)
    const int nb = nkd[m0 >> 11];
#pragma unroll
    for (int mi = 0; mi < 4; ++mi)
#pragma unroll
      for (int r = 0; r < 4; ++r) {
        const int m = cm + 16 * mi + r;
        const bool ok = (m & 2047) < nb;
        OT* row = C + (size_t)m * 1024;
#pragma unroll
        for (int ni = 0; ni < 4; ++ni)
          row[cn + 16 * ni] = ok ? (OT)(acc[mi][ni][r] + bv[ni]) : (OT)0.f;
      }
  }
}

// ---------------------------------------------------------------------------
// vtrans: transpose compacted V. vhT[bh][dh][j] = vhc[b*T+j][h*64+dh],
// zeros for pad j; tiles >= nkt untouched (attn never reads them).
// ---------------------------------------------------------------------------
__global__ __launch_bounds__(256) void vtrans(
    const f16* __restrict__ vhc, const int* __restrict__ nk,
    f16* __restrict__ vhT) {
  const int tt = blockIdx.x, bh = blockIdx.y;
  const int b = bh >> 4, h = bh & 15;
  const int n = nk[b];
  const int nkt = (n + 63) >> 6;
  if (tt >= nkt) return;
  __shared__ f16 t[64][72];
  const int tid = threadIdx.x;
  const int r = tid >> 2, cq = 16 * (tid & 3);

  const int j = tt * 64 + r;
  uint4 v0 = {0u, 0u, 0u, 0u}, v1 = {0u, 0u, 0u, 0u};
  if (j < n) {
    const uint4* src = (const uint4*)(vhc + ((size_t)b * T_ + j) * D_ + h * 64 + cq);
    v0 = src[0]; v1 = src[1];
  }
  *(uint4*)&t[r][cq]     = v0;
  *(uint4*)&t[r][cq + 8] = v1;
  __syncthreads();

  f16 tmp[16];
#pragma unroll
  for (int xx = 0; xx < 16; ++xx) {
    int x = (xx + r) & 15;
    tmp[x] = t[cq + x][r];
  }
  f16* dst = vhT + ((size_t)bh * 64 + r) * T_ + tt * 64 + cq;
  *(uint4*)&dst[0] = *(uint4*)&tmp[0];
  *(uint4*)&dst[8] = *(uint4*)&tmp[8];
}

// ---------------------------------------------------------------------------
// Flash attention over compacted keys. Block = 128 q-rows (grid 16 x 32),
// 512 threads / 8 waves; each wave owns 16 q-rows. 16 waves/CU.
// Q frags direct from global, cached in regs. qh pre-scaled by SCALE*log2e
// -> P = exp2(S); pad keys contribute p=1, corrected via lsum -= npad.
// ---------------------------------------------------------------------------
__global__ __launch_bounds__(512) void attn_mfma(
    const f16* __restrict__ qh, const f16* __restrict__ khc,
    const f16* __restrict__ vhT, const int* __restrict__ nkd,
    f16* __restrict__ oat) {
  __shared__ f16 Ks[64][72];     // [key][dh]
  __shared__ f16 Vt[64][72];     // [dh][key]
  __shared__ f16 Ps[8][16][72];  // per-wave [qrow][key]

  const int qt = blockIdx.x, bh = blockIdx.y;
  const int b = bh >> 4, h = bh & 15;
  const int tid = threadIdx.x;
  const int wave = tid >> 6, lane = tid & 63;
  const int quad = lane >> 4, l16 = lane & 15;
  const int sr = tid >> 3, sq = 8 * (tid & 7);  // 512 thr: 1 uint4 each for K,V

  const int n = nkd[b];
  const int nkt = (n + 63) >> 6;
  const int npad = (nkt << 6) - n;

  // Q fragments direct from global: row qt*128 + wave*16 + l16
  f16x8 qf[2];
  {
    const f16* qp = qh + ((size_t)(b * T_ + qt * 128 + wave * 16 + l16)) * D_ + h * 64 + quad * 8;
    qf[0] = *(const f16x8*)qp;
    qf[1] = *(const f16x8*)(qp + 32);
  }

  float lsum = 0.f;
  f32x4 o[4] = {};

  const f16* kbase = khc + (size_t)b * T_ * D_ + h * 64;
  const f16* vbase = vhT + ((size_t)bh * 64 + sr) * T_;

  uint4 kr, vr;
  auto load_kv = [&](int kt) {
    kr = *(const uint4*)(kbase + (size_t)(kt * 64 + sr) * D_ + sq);
    vr = *(const uint4*)(vbase + kt * 64 + sq);
  };
  if (nkt > 0) load_kv(0);

  for (int kt = 0; kt < nkt; ++kt) {
    *(uint4*)&Ks[sr][sq] = kr;
    *(uint4*)&Vt[sr][sq] = vr;
    __syncthreads();
    if (kt + 1 < nkt) load_kv(kt + 1);  // prefetch next tile into regs

    // ---- S^T = K Q^T : D[m=key][n=qrow] ----
#pragma unroll
    for (int tn = 0; tn < 4; ++tn) {
      f16x8 kf0 = *(const f16x8*)&Ks[16 * tn + l16][quad * 8];
      f16x8 kf1 = *(const f16x8*)&Ks[16 * tn + l16][32 + quad * 8];
      f32x4 s = {0.f, 0.f, 0.f, 0.f};
      s = __builtin_amdgcn_mfma_f32_16x16x32_f16(kf0, qf[0], s, 0, 0, 0);
      s = __builtin_amdgcn_mfma_f32_16x16x32_f16(kf1, qf[1], s, 0, 0, 0);
      float p0 = exp2f(s[0]), p1 = exp2f(s[1]);
      float p2 = exp2f(s[2]), p3 = exp2f(s[3]);
      lsum += (p0 + p1) + (p2 + p3);
      f16x4 pk;
      pk[0] = (f16)p0; pk[1] = (f16)p1; pk[2] = (f16)p2; pk[3] = (f16)p3;
      *(f16x4*)&Ps[wave][l16][16 * tn + 4 * quad] = pk;
    }

    // ---- O += P V ----
    f16x8 pf0 = *(const f16x8*)&Ps[wave][l16][quad * 8];
    f16x8 pf1 = *(const f16x8*)&Ps[wave][l16][32 + quad * 8];
#pragma unroll
    for (int t = 0; t < 4; ++t) {
      f16x8 vf0 = *(const f16x8*)&Vt[16 * t + l16][quad * 8];
      f16x8 vf1 = *(const f16x8*)&Vt[16 * t + l16][32 + quad * 8];
      o[t] = __builtin_amdgcn_mfma_f32_16x16x32_f16(pf0, vf0, o[t], 0, 0, 0);
      o[t] = __builtin_amdgcn_mfma_f32_16x16x32_f16(pf1, vf1, o[t], 0, 0, 0);
    }
    __syncthreads();
  }

  {
    float ls = lsum;
    ls += __shfl_xor(ls, 16);   // quads hold disjoint key subsets
    ls += __shfl_xor(ls, 32);
    ls -= (float)npad;
    const size_t orow = (size_t)(b * T_ + qt * 128 + wave * 16 + 4 * quad);
#pragma unroll
    for (int r = 0; r < 4; ++r) {
      const float iv = 1.f / __shfl(ls, 4 * quad + r);
#pragma unroll
      for (int t = 0; t < 4; ++t)
        oat[(orow + r) * D_ + h * 64 + 16 * t + l16] = (f16)(o[t][r] * iv);
    }
  }
}

// ---------------------------------------------------------------------------
extern "C" void kernel_launch(void* const* d_in, const int* in_sizes, int n_in,
                              void* d_out, int out_size, void* d_ws, size_t ws_size,
                              hipStream_t stream) {
  const float* q  = (const float*)d_in[0];
  const float* k  = (const float*)d_in[1];
  const float* v  = (const float*)d_in[2];
  const int* mask = (const int*)d_in[3];
  const float* Wq = (const float*)d_in[4];
  const float* bq = (const float*)d_in[5];
  const float* Wk = (const float*)d_in[6];
  const float* bk = (const float*)d_in[7];
  const float* Wv = (const float*)d_in[8];
  const float* bv = (const float*)d_in[9];
  const float* Wo = (const float*)d_in[10];
  const float* bo = (const float*)d_in[11];
  float* out = (float*)d_out;

  // ws layout (bytes):
  //  0        xq (8MB)  -> vhT after gemm
  //  8388608  xkc (8MB) -> oat after gemm
  //  16777216 xvc (8MB)
  //  25165824 Wt (8MB)
  //  33554432 qh (8MB)
  //  41943040 vhc (8MB)
  //  50331648 khc (8MB)
  //  58720256 bias(16KB) | inv(16KB) | nk(8B)
  char* ws = (char*)d_ws;
  f16* xqkv  = (f16*)(ws);
  f16* Wt    = (f16*)(ws + 25165824);
  f16* qh    = (f16*)(ws + 33554432);
  f16* vhc   = (f16*)(ws + 41943040);
  f16* khc   = (f16*)(ws + 50331648);
  float* bsw = (float*)(ws + 58720256);
  int* inv   = (int*)(ws + 58736640);
  int* nk    = (int*)(ws + 58753024);
  f16* vhT   = (f16*)(ws);             // aliases xq (dead after gemm)
  f16* oat   = (f16*)(ws + 8388608);   // aliases xkc (dead after gemm)

  dim3 blk(256);

  prep0<<<dim3(2), blk, 0, stream>>>(mask, inv, nk);

  prep1<<<dim3(7184), blk, 0, stream>>>(q, k, v, inv, Wq, Wk, Wv, Wo,
                                        bq, bk, bv, bo, xqkv, Wt, bsw);

  gemm_r4<f16, true><<<dim3(8, 32, 3), blk, 0, stream>>>(
      xqkv, Wt, bsw, qh, khc, vhc, nk, QSCALE);

  vtrans<<<dim3(32, 32), blk, 0, stream>>>(vhc, nk, vhT);

  attn_mfma<<<dim3(16, 32), dim3(512), 0, stream>>>(qh, khc, vhT, nk, oat);

  gemm_r4<float, false><<<dim3(8, 32, 1), blk, 0, stream>>>(
      oat, Wt + 3145728, bsw + 3072, out, nullptr, nullptr, nullptr, 1.f);
}

// Round 10
// 209.517 us; speedup vs baseline: 1.0692x; 1.0356x over previous
//
#include <hip/hip_runtime.h>
#include <hip/hip_bf16.h>
#include <math.h>

#define B_ 2
#define T_ 2048
#define D_ 1024
#define H_ 16
#define QSCALE (0.03125f * 1.44269504088896f)  // 1/sqrt(1024) * log2(e)

typedef _Float16 f16;
using f16x4 = __attribute__((ext_vector_type(4))) _Float16;
using f16x8 = __attribute__((ext_vector_type(8))) _Float16;
using f32x4 = __attribute__((ext_vector_type(4))) float;

__device__ __forceinline__ void gl16(const void* g, void* l) {
  __builtin_amdgcn_global_load_lds(
      (__attribute__((address_space(1))) void*)g,
      (__attribute__((address_space(3))) void*)l, 16, 0, 0);
}

__device__ __forceinline__ unsigned lds_a32(const void* p) {
  return (unsigned)(size_t)(__attribute__((address_space(3))) const char*)p;
}

// ---------------------------------------------------------------------------
// prep0: mask scan -> inv (compacted position per masked row, -1 if dropped)
// + nk (count per batch). One block per batch. Must run before prep1.
// ---------------------------------------------------------------------------
__global__ __launch_bounds__(256) void prep0(
    const int* __restrict__ mask, int* __restrict__ inv, int* __restrict__ nk) {
  __shared__ int cnt[256];
  const int b = blockIdx.x;
  const int tid = threadIdx.x;
  int loc[8];
  int c = 0;
#pragma unroll
  for (int i = 0; i < 8; ++i) {
    loc[i] = mask[b * T_ + tid * 8 + i];
    c += loc[i];
  }
  cnt[tid] = c;
  __syncthreads();
  for (int off = 1; off < 256; off <<= 1) {
    int vsh = (tid >= off) ? cnt[tid - off] : 0;
    __syncthreads();
    cnt[tid] += vsh;
    __syncthreads();
  }
  int pos = cnt[tid] - c;  // exclusive prefix
#pragma unroll
  for (int i = 0; i < 8; ++i) {
    const int t = tid * 8 + i;
    inv[b * T_ + t] = loc[i] ? pos : -1;
    pos += loc[i];
  }
  if (tid == 255) nk[b] = cnt[255];
}

// ---------------------------------------------------------------------------
// prep1: cvt_x (0..6143) + cvt_w transpose (6144..7167) + pack_bias
// (7168..7183). k/v conversion COMPACTS rows through inv; dropped rows
// skipped. Rows [n, nkt*64) of xkc/xvc stay garbage; the GEMM epilogue
// masks them to 0.
// ---------------------------------------------------------------------------
__global__ __launch_bounds__(256) void prep1(
    const float* __restrict__ q, const float* __restrict__ k,
    const float* __restrict__ v, const int* __restrict__ inv,
    const float* __restrict__ Wq, const float* __restrict__ Wk,
    const float* __restrict__ Wv, const float* __restrict__ Wo,
    const float* __restrict__ bq, const float* __restrict__ bk,
    const float* __restrict__ bv, const float* __restrict__ bo,
    f16* __restrict__ xqkv, f16* __restrict__ Wt, float* __restrict__ bias) {
  __shared__ float sh[64][65];
  const int bid = blockIdx.x;
  const int tid = threadIdx.x;

  if (bid < 6144) {  // ---- cvt_x: fp32 -> f16 (k/v: compacted scatter) ----
    const int z = bid / 2048;
    const float* src = (z == 0) ? q : (z == 1) ? k : v;
    const size_t i = ((size_t)(bid % 2048) * 256 + tid) * 8;
    float4 a = *(const float4*)(src + i);
    float4 b4 = *(const float4*)(src + i + 4);
    f16x8 o;
    o[0] = (f16)a.x;  o[1] = (f16)a.y;  o[2] = (f16)a.z;  o[3] = (f16)a.w;
    o[4] = (f16)b4.x; o[5] = (f16)b4.y; o[6] = (f16)b4.z; o[7] = (f16)b4.w;
    if (z == 0) {
      *(f16x8*)(xqkv + i) = o;
    } else {
      const int tl = (int)(i >> 10);          // global row 0..4095
      const int bb = tl >> 11, t = tl & 2047;
      const int j = inv[bb * T_ + t];
      if (j >= 0)
        *(f16x8*)(xqkv + (size_t)z * 4194304 +
                  (((size_t)(bb * T_ + j)) << 10) + (i & 1023)) = o;
    }
  } else if (bid < 7168) {  // ---- cvt_w: W[K][N] fp32 -> Wt[N][K] f16 ----
    const int id = bid - 6144;
    const int z = id >> 8;
    const int k0 = ((id >> 4) & 15) * 64, n0 = (id & 15) * 64;
    const float* W = (z == 0) ? Wq : (z == 1) ? Wk : (z == 2) ? Wv : Wo;
    const int r = tid >> 2, c0 = (tid & 3) * 16;
#pragma unroll
    for (int i = 0; i < 4; ++i)
      *(float4*)&sh[r][c0 + 4 * i] =
          *(const float4*)&W[(size_t)(k0 + r) * 1024 + n0 + c0 + 4 * i];
    __syncthreads();
    f16 tmp[16];
#pragma unroll
    for (int i = 0; i < 16; ++i) tmp[i] = (f16)sh[c0 + i][r];
    f16* dst = Wt + (size_t)z * 1048576 + (size_t)(n0 + r) * 1024 + k0 + c0;
    *(f16x8*)dst = *(f16x8*)&tmp[0];
    *(f16x8*)(dst + 8) = *(f16x8*)&tmp[8];
  } else {  // ---- pack_bias ----
    const int i = (bid - 7168) * 256 + tid;
    const int z = i >> 10;
    const float* s = (z == 0) ? bq : (z == 1) ? bk : (z == 2) ? bv : bo;
    bias[i] = s[i & 1023];
  }
}

// ---------------------------------------------------------------------------
// gemm_r4: 128 x (32*FN) tile, BK=32, 256 thr / 4 waves (2M x 2N), ring-4
// LDS (fixed 64KB -> 2 blocks/CU resident + queue backfill, the round-9
// verified balancing mechanism). asm ds_read_b128, bare counted waitcnts,
// asm s_barrier, XOR swizzle both-sides (0 conflicts, verified).
// FN=4: 128-wide N tile (QKV). FN=2: 64-wide N tile (out-proj; 512-block
// grid -> 2/CU + backfill instead of 1/CU with no overlap).
// CMP: z>=1 K/V compaction (early-exit beyond nkt*64; epilogue masks rows
// j>=n to 0). ROUND 10: z==2 (V) writes TRANSPOSED output directly to
// vhT[(b*16+h)*64+dh][j] as f16x4 (r is j-contiguous in registers) --
// eliminates the vtrans kernel and the vhc round-trip entirely.
// Ring-4 safety: tile t+4 reuses slot t&3 only after COMPUTE(t)'s
// lgkmcnt(0)+barrier retired all reads. vmcnt main = 3 tiles in flight x
// loads/tile (FN=4: 12, FN=2: 9).
// ---------------------------------------------------------------------------
template <typename OT, bool CMP, int FN>
__global__ __launch_bounds__(256, 4) void gemm_r4(
    const f16* __restrict__ Xb, const f16* __restrict__ Wtb,
    const float* __restrict__ biasb, void* __restrict__ C0,
    void* __restrict__ C1, void* __restrict__ C2,
    const int* __restrict__ nkd, float qscale) {
  static_assert(FN == 2 || FN == 4, "FN must be 2 or 4");
  __shared__ __align__(16) char lds[65536];  // 4 x [A 8K | B <=8K]
  const int z = blockIdx.z;
  const int m0 = blockIdx.y * 128, n0 = blockIdx.x * (32 * FN);

  if (CMP && z) {  // compacted K/V: skip blocks beyond this batch's live rows
    const int nb = nkd[m0 >> 11];
    const int lim = ((nb + 63) >> 6) << 6;  // nkt*64
    if ((m0 & 2047) >= lim) return;
  }

  const f16* X  = Xb  + (size_t)z * (4096 * 1024);
  const f16* Wt = Wtb + (size_t)z * (1024 * 1024);
  const float* bias = biasb + (size_t)z * 1024;
  OT* C = (OT*)((z == 0) ? C0 : (z == 1) ? C1 : C2);
  const float scl = (z == 0) ? qscale : 1.f;

  const int tid = threadIdx.x;
  const int wave = tid >> 6, lane = tid & 63;
  const int quad = lane >> 4, l16 = lane & 15;
  const int wm = wave & 1, wn = wave >> 1;  // 2 x 2 wave grid

  // staging: 256 threads x 16B = rows 0..63 of a panel; A's second gl16 at
  // +4096 covers rows 64..127. src chunk = (tid&3) ^ ((row>>1)&3)
  const int r0 = tid >> 2;
  const int ssw = (tid & 3) ^ ((r0 >> 1) & 3);
  const f16* ap0 = X  + (size_t)(m0 + r0) * 1024 + ssw * 8;
  const f16* ap1 = ap0 + (size_t)64 * 1024;
  const f16* bp0 = Wt + (size_t)(n0 + r0) * 1024 + ssw * 8;
  const f16* bp1 = bp0 + (size_t)64 * 1024;  // used only when FN==4
  char* al = lds + tid * 16;
  char* bl = lds + 8192 + tid * 16;

  // read-side swizzle: frag at (row, quad) reads chunk quad ^ ((l16>>1)&3)
  const int sw16 = 16 * (quad ^ ((l16 >> 1) & 3));
  const unsigned a32 = lds_a32(lds + (64 * wm + l16) * 64 + sw16);
  const unsigned b32 = lds_a32(lds + 8192 + (16 * FN * wn + l16) * 64 + sw16);

  f32x4 acc[4][FN] = {};

#define R4_ISSUE(tt, sl) do {                                               \
    gl16(ap0 + (tt) * 32, al + (sl) * 16384);                               \
    gl16(ap1 + (tt) * 32, al + (sl) * 16384 + 4096);                        \
    gl16(bp0 + (tt) * 32, bl + (sl) * 16384);                               \
    if constexpr (FN == 4) gl16(bp1 + (tt) * 32, bl + (sl) * 16384 + 4096); \
    __builtin_amdgcn_sched_barrier(0);                                      \
  } while (0)

#define R4_WAITM() do {                                                     \
    if constexpr (FN == 4) { asm volatile("s_waitcnt vmcnt(12)"); }         \
    else                   { asm volatile("s_waitcnt vmcnt(9)");  }         \
    __builtin_amdgcn_sched_barrier(0);                                      \
  } while (0)

#define R4_WAITE(n4, n2) do {                                               \
    if constexpr (FN == 4) { asm volatile("s_waitcnt vmcnt(" #n4 ")"); }    \
    else                   { asm volatile("s_waitcnt vmcnt(" #n2 ")"); }    \
    __builtin_amdgcn_sched_barrier(0);                                      \
  } while (0)

#define R4_BAR() do {                                                       \
    __builtin_amdgcn_sched_barrier(0);                                      \
    asm volatile("s_barrier");                                              \
    __builtin_amdgcn_sched_barrier(0);                                      \
  } while (0)

#define R4_STR_(x) #x
#define R4_STR(x) R4_STR_(x)
#define DSR(dst, base, OFF)                                                 \
  asm volatile("ds_read_b128 %0, %1 offset:" R4_STR(OFF)                    \
               : "=v"(dst) : "v"(base))

#define R4_COMPUTE(sl) do {                                                 \
    R4_BAR();                                                               \
    const unsigned aa = a32 + (sl) * 16384;                                 \
    const unsigned bb = b32 + (sl) * 16384;                                 \
    f16x8 af[4], bf[FN];                                                    \
    DSR(af[0], aa, 0);    DSR(af[1], aa, 1024);                             \
    DSR(bf[0], bb, 0);    DSR(bf[1], bb, 1024);                             \
    if constexpr (FN == 4) { DSR(bf[2], bb, 2048); DSR(bf[3], bb, 3072); }  \
    DSR(af[2], aa, 2048); DSR(af[3], aa, 3072);                             \
    asm volatile("s_waitcnt lgkmcnt(2)");                                   \
    __builtin_amdgcn_sched_barrier(0);                                      \
    __builtin_amdgcn_s_setprio(1);                                          \
    _Pragma("unroll")                                                       \
    for (int mi = 0; mi < 2; ++mi)                                          \
      _Pragma("unroll")                                                     \
      for (int ni = 0; ni < FN; ++ni)                                       \
        acc[mi][ni] = __builtin_amdgcn_mfma_f32_16x16x32_f16(               \
            af[mi], bf[ni], acc[mi][ni], 0, 0, 0);                          \
    asm volatile("s_waitcnt lgkmcnt(0)");                                   \
    __builtin_amdgcn_sched_barrier(0);                                      \
    _Pragma("unroll")                                                       \
    for (int mi = 2; mi < 4; ++mi)                                          \
      _Pragma("unroll")                                                     \
      for (int ni = 0; ni < FN; ++ni)                                       \
        acc[mi][ni] = __builtin_amdgcn_mfma_f32_16x16x32_f16(               \
            af[mi], bf[ni], acc[mi][ni], 0, 0, 0);                          \
    __builtin_amdgcn_s_setprio(0);                                          \
    R4_BAR();                                                               \
  } while (0)

  // K = 1024 -> 32 K-tiles of 32. Ring-4: slot = tile & 3; 3 tiles ahead.
  R4_ISSUE(0, 0); R4_ISSUE(1, 1); R4_ISSUE(2, 2);

  for (int j = 0; j < 7; ++j) {  // tiles 4j .. 4j+3 (0..27)
    const int t4 = j * 4;
    R4_ISSUE(t4 + 3, 3); R4_WAITM(); R4_COMPUTE(0);
    R4_ISSUE(t4 + 4, 0); R4_WAITM(); R4_COMPUTE(1);
    R4_ISSUE(t4 + 5, 1); R4_WAITM(); R4_COMPUTE(2);
    R4_ISSUE(t4 + 6, 2); R4_WAITM(); R4_COMPUTE(3);
  }
  R4_ISSUE(31, 3); R4_WAITM(); R4_COMPUTE(0);  // tile 28
  R4_WAITE(8, 6);  R4_COMPUTE(1);              // tile 29
  R4_WAITE(4, 3);  R4_COMPUTE(2);              // tile 30
  R4_WAITE(0, 0);  R4_COMPUTE(3);              // tile 31

#undef R4_ISSUE
#undef R4_WAITM
#undef R4_WAITE
#undef R4_BAR
#undef DSR
#undef R4_STR
#undef R4_STR_
#undef R4_COMPUTE

  const int cm = m0 + 64 * wm + 4 * quad;
  const int cn = n0 + 16 * FN * wn + l16;
  float bv[FN];
#pragma unroll
  for (int ni = 0; ni < FN; ++ni) bv[ni] = bias[cn + 16 * ni];

  if (!CMP || z == 0) {
#pragma unroll
    for (int mi = 0; mi < 4; ++mi)
#pragma unroll
      for (int r = 0; r < 4; ++r) {
        OT* row = C + (size_t)(cm + 16 * mi + r) * 1024;
#pragma unroll
        for (int ni = 0; ni < FN; ++ni)
          row[cn + 16 * ni] = (OT)((acc[mi][ni][r] + bv[ni]) * scl);
      }
  } else if (z == 1) {  // khc: rows j >= n masked to 0 (pad-key semantics)
    const int nb = nkd[m0 >> 11];
#pragma unroll
    for (int mi = 0; mi < 4; ++mi)
#pragma unroll
      for (int r = 0; r < 4; ++r) {
        const int m = cm + 16 * mi + r;
        const bool ok = (m & 2047) < nb;
        OT* row = C + (size_t)m * 1024;
#pragma unroll
        for (int ni = 0; ni < FN; ++ni)
          row[cn + 16 * ni] = ok ? (OT)(acc[mi][ni][r] + bv[ni]) : (OT)0.f;
      }
  } else {  // z == 2: fused V transpose -> vhT[(b*16+h)*64+dh][j], f16x4
    const int nb = nkd[m0 >> 11];
    const int bb = m0 >> 11;
    const int jb = cm & 2047;  // j base for r=0..3 (contiguous)
#pragma unroll
    for (int mi = 0; mi < 4; ++mi) {
      const int j0 = jb + 16 * mi;
#pragma unroll
      for (int ni = 0; ni < FN; ++ni) {
        const int c = cn + 16 * ni;
        f16x4 pk;
#pragma unroll
        for (int r = 0; r < 4; ++r)
          pk[r] = (j0 + r < nb) ? (f16)(acc[mi][ni][r] + bv[ni]) : (f16)0.f;
        f16* dst = (f16*)C +
            (((size_t)(bb * 16 + (c >> 6)) * 64 + (c & 63)) << 11) + j0;
        *(f16x4*)dst = pk;
      }
    }
  }
}

// ---------------------------------------------------------------------------
// Flash attention over compacted keys. Block = 128 q-rows (grid 16 x 32),
// 512 threads / 8 waves; each wave owns 16 q-rows. 16 waves/CU.
// Q frags direct from global, cached in regs. qh pre-scaled by SCALE*log2e
// -> P = exp2(S); pad keys contribute p=1, corrected via lsum -= npad.
// ---------------------------------------------------------------------------
__global__ __launch_bounds__(512) void attn_mfma(
    const f16* __restrict__ qh, const f16* __restrict__ khc,
    const f16* __restrict__ vhT, const int* __restrict__ nkd,
    f16* __restrict__ oat) {
  __shared__ f16 Ks[64][72];     // [key][dh]
  __shared__ f16 Vt[64][72];     // [dh][key]
  __shared__ f16 Ps[8][16][72];  // per-wave [qrow][key]

  const int qt = blockIdx.x, bh = blockIdx.y;
  const int b = bh >> 4, h = bh & 15;
  const int tid = threadIdx.x;
  const int wave = tid >> 6, lane = tid & 63;
  const int quad = lane >> 4, l16 = lane & 15;
  const int sr = tid >> 3, sq = 8 * (tid & 7);  // 512 thr: 1 uint4 each for K,V

  const int n = nkd[b];
  const int nkt = (n + 63) >> 6;
  const int npad = (nkt << 6) - n;

  // Q fragments direct from global: row qt*128 + wave*16 + l16
  f16x8 qf[2];
  {
    const f16* qp = qh + ((size_t)(b * T_ + qt * 128 + wave * 16 + l16)) * D_ + h * 64 + quad * 8;
    qf[0] = *(const f16x8*)qp;
    qf[1] = *(const f16x8*)(qp + 32);
  }

  float lsum = 0.f;
  f32x4 o[4] = {};

  const f16* kbase = khc + (size_t)b * T_ * D_ + h * 64;
  const f16* vbase = vhT + ((size_t)bh * 64 + sr) * T_;

  uint4 kr, vr;
  auto load_kv = [&](int kt) {
    kr = *(const uint4*)(kbase + (size_t)(kt * 64 + sr) * D_ + sq);
    vr = *(const uint4*)(vbase + kt * 64 + sq);
  };
  if (nkt > 0) load_kv(0);

  for (int kt = 0; kt < nkt; ++kt) {
    *(uint4*)&Ks[sr][sq] = kr;
    *(uint4*)&Vt[sr][sq] = vr;
    __syncthreads();
    if (kt + 1 < nkt) load_kv(kt + 1);  // prefetch next tile into regs

    // ---- S^T = K Q^T : D[m=key][n=qrow] ----
#pragma unroll
    for (int tn = 0; tn < 4; ++tn) {
      f16x8 kf0 = *(const f16x8*)&Ks[16 * tn + l16][quad * 8];
      f16x8 kf1 = *(const f16x8*)&Ks[16 * tn + l16][32 + quad * 8];
      f32x4 s = {0.f, 0.f, 0.f, 0.f};
      s = __builtin_amdgcn_mfma_f32_16x16x32_f16(kf0, qf[0], s, 0, 0, 0);
      s = __builtin_amdgcn_mfma_f32_16x16x32_f16(kf1, qf[1], s, 0, 0, 0);
      float p0 = exp2f(s[0]), p1 = exp2f(s[1]);
      float p2 = exp2f(s[2]), p3 = exp2f(s[3]);
      lsum += (p0 + p1) + (p2 + p3);
      f16x4 pk;
      pk[0] = (f16)p0; pk[1] = (f16)p1; pk[2] = (f16)p2; pk[3] = (f16)p3;
      *(f16x4*)&Ps[wave][l16][16 * tn + 4 * quad] = pk;
    }

    // ---- O += P V ----
    f16x8 pf0 = *(const f16x8*)&Ps[wave][l16][quad * 8];
    f16x8 pf1 = *(const f16x8*)&Ps[wave][l16][32 + quad * 8];
#pragma unroll
    for (int t = 0; t < 4; ++t) {
      f16x8 vf0 = *(const f16x8*)&Vt[16 * t + l16][quad * 8];
      f16x8 vf1 = *(const f16x8*)&Vt[16 * t + l16][32 + quad * 8];
      o[t] = __builtin_amdgcn_mfma_f32_16x16x32_f16(pf0, vf0, o[t], 0, 0, 0);
      o[t] = __builtin_amdgcn_mfma_f32_16x16x32_f16(pf1, vf1, o[t], 0, 0, 0);
    }
    __syncthreads();
  }

  {
    float ls = lsum;
    ls += __shfl_xor(ls, 16);   // quads hold disjoint key subsets
    ls += __shfl_xor(ls, 32);
    ls -= (float)npad;
    const size_t orow = (size_t)(b * T_ + qt * 128 + wave * 16 + 4 * quad);
#pragma unroll
    for (int r = 0; r < 4; ++r) {
      const float iv = 1.f / __shfl(ls, 4 * quad + r);
#pragma unroll
      for (int t = 0; t < 4; ++t)
        oat[(orow + r) * D_ + h * 64 + 16 * t + l16] = (f16)(o[t][r] * iv);
    }
  }
}

// ---------------------------------------------------------------------------
extern "C" void kernel_launch(void* const* d_in, const int* in_sizes, int n_in,
                              void* d_out, int out_size, void* d_ws, size_t ws_size,
                              hipStream_t stream) {
  const float* q  = (const float*)d_in[0];
  const float* k  = (const float*)d_in[1];
  const float* v  = (const float*)d_in[2];
  const int* mask = (const int*)d_in[3];
  const float* Wq = (const float*)d_in[4];
  const float* bq = (const float*)d_in[5];
  const float* Wk = (const float*)d_in[6];
  const float* bk = (const float*)d_in[7];
  const float* Wv = (const float*)d_in[8];
  const float* bv = (const float*)d_in[9];
  const float* Wo = (const float*)d_in[10];
  const float* bo = (const float*)d_in[11];
  float* out = (float*)d_out;

  // ws layout (bytes):
  //  0        xq (8MB)
  //  8388608  xkc (8MB) -> oat after gemm
  //  16777216 xvc (8MB)
  //  25165824 Wt (8MB)
  //  33554432 qh (8MB)
  //  41943040 vhT (8MB)   (written directly by gemm z=2 fused transpose)
  //  50331648 khc (8MB)
  //  58720256 bias(16KB) | inv(16KB) | nk(8B)
  char* ws = (char*)d_ws;
  f16* xqkv  = (f16*)(ws);
  f16* Wt    = (f16*)(ws + 25165824);
  f16* qh    = (f16*)(ws + 33554432);
  f16* vhT   = (f16*)(ws + 41943040);
  f16* khc   = (f16*)(ws + 50331648);
  float* bsw = (float*)(ws + 58720256);
  int* inv   = (int*)(ws + 58736640);
  int* nk    = (int*)(ws + 58753024);
  f16* oat   = (f16*)(ws + 8388608);   // aliases xkc (dead after gemm)

  dim3 blk(256);

  prep0<<<dim3(2), blk, 0, stream>>>(mask, inv, nk);

  prep1<<<dim3(7184), blk, 0, stream>>>(q, k, v, inv, Wq, Wk, Wv, Wo,
                                        bq, bk, bv, bo, xqkv, Wt, bsw);

  gemm_r4<f16, true, 4><<<dim3(8, 32, 3), blk, 0, stream>>>(
      xqkv, Wt, bsw, qh, khc, vhT, nk, QSCALE);

  attn_mfma<<<dim3(16, 32), dim3(512), 0, stream>>>(qh, khc, vhT, nk, oat);

  gemm_r4<float, false, 2><<<dim3(16, 32, 1), blk, 0, stream>>>(
      oat, Wt + 3145728, bsw + 3072, out, nullptr, nullptr, nullptr, 1.f);
}